// Round 8
// baseline (113.467 us; speedup 1.0000x reference)
//
#include <hip/hip_runtime.h>
#include <math.h>

#define N_    16
#define C_    256
#define H_    56
#define W_    56
#define HW_   3136          // H_*W_
#define NPIX  50176         // N_*HW_
#define OUTC  512
#define SPAN_ 2304          // C_*9
#define BLKPX 256           // conv block pixel tile
#define HBYTES 24576        // one halo buffer: 384 slots * 64 B
#define ZOFF  (2 * HBYTES)  // 64-B zero slot after both buffers

typedef unsigned short u16;
typedef unsigned int   u32;
typedef __attribute__((ext_vector_type(8))) short bf16x8;
typedef __attribute__((ext_vector_type(8))) unsigned short u16x8;
typedef __attribute__((ext_vector_type(4))) float f32x4;
typedef __attribute__((ext_vector_type(4))) unsigned short u16x4;

__device__ __forceinline__ u16 f2bf(float v) {
    u32 x = __float_as_uint(v);
    u32 r = (x + 0x7fffu + ((x >> 16) & 1u)) >> 16;   // RNE
    return (u16)r;
}

__device__ __forceinline__ int bucketf(float v, float b) {
    int idx = (int)floorf((v + b) / 2.5f);
    int r = idx % 8;
    return r < 0 ? -r : r;
}

// ---- Kernel A: bucket of each kernel row ------------------------------------
__global__ void kbucket_kernel(const float* __restrict__ kern,
                               const float* __restrict__ ah,
                               const float* __restrict__ bh,
                               int* __restrict__ kbuck) {
    int oc = blockIdx.x;
    const float* kr = kern + (size_t)oc * SPAN_;
    float dot = 0.f, ss = 0.f;
    for (int j = threadIdx.x; j < SPAN_; j += 64) {
        float kv = kr[j];
        dot += kv * ah[j];
        ss  += kv * kv;
    }
    for (int o = 32; o; o >>= 1) {
        dot += __shfl_down(dot, o);
        ss  += __shfl_down(ss, o);
    }
    if (threadIdx.x == 0) {
        float n2 = ss;            // ||k||^2
        float n4 = n2 * n2;
        float n8 = n4 * n4;
        float v = dot + n2 * ah[SPAN_] + n4 * ah[SPAN_ + 1] + n8 * ah[SPAN_ + 2];
        kbuck[oc] = bucketf(v, bh[0]);
    }
}

// ---- Kernel P1+B1 fused: NCHW f32 -> NHWC bf16, tap maps g[9], sumsq s2 -----
__global__ __launch_bounds__(256) void prep_fused(const float* __restrict__ x,
                                                  const float* __restrict__ ah,
                                                  u16* __restrict__ xp,
                                                  float* __restrict__ g,
                                                  float* __restrict__ s2) {
    __shared__ float aL[SPAN_];          // 9216 B
    __shared__ u16 tl[64][68];           // 8704 B
    __shared__ float red[4][64][10];     // 10240 B
    int t = threadIdx.x;
    for (int j = t; j < SPAN_; j += 256) aL[j] = ah[j];

    int px0 = blockIdx.x * 64;
    int img = px0 / HW_;
    int hw0 = px0 - img * HW_;
    int px_l = t & 63;
    int cq   = t >> 6;                   // 0..3
    float pg[9];
#pragma unroll
    for (int kk = 0; kk < 9; ++kk) pg[kk] = 0.f;
    float ps = 0.f;
    __syncthreads();

    for (int cb0 = 0; cb0 < 4; ++cb0) {
        int c0 = cb0 * 64;
#pragma unroll
        for (int rep = 0; rep < 16; ++rep) {
            int c_l = rep * 4 + cq;
            float v = x[((size_t)(img * C_ + c0 + c_l)) * HW_ + hw0 + px_l];
            tl[px_l][c_l] = f2bf(v);
            const float* ac = &aL[(c0 + c_l) * 9];
#pragma unroll
            for (int kk = 0; kk < 9; ++kk) pg[kk] += ac[kk] * v;
            ps += v * v;
        }
        __syncthreads();
        int c4  = t & 15;
        int pxs = t >> 4;
#pragma unroll
        for (int rep = 0; rep < 4; ++rep) {
            int pl = rep * 16 + pxs;
            u16x4 v4 = *(const u16x4*)(&tl[pl][c4 * 4]);
            *(u16x4*)(&xp[((size_t)(px0 + pl)) * C_ + c0 + c4 * 4]) = v4;
        }
        __syncthreads();
    }

#pragma unroll
    for (int kk = 0; kk < 9; ++kk) red[cq][px_l][kk] = pg[kk];
    red[cq][px_l][9] = ps;
    __syncthreads();
    for (int it = t; it < 640; it += 256) {
        int pl = it / 10;
        int j  = it - pl * 10;
        float s = red[0][pl][j] + red[1][pl][j] + red[2][pl][j] + red[3][pl][j];
        int q = px0 + pl;
        if (j < 9) g[(size_t)j * NPIX + q] = s;
        else       s2[q] = s;
    }
}

// ---- Kernel B2: per-column vote -> histogram --------------------------------
__global__ __launch_bounds__(256) void vote_kernel(const float* __restrict__ g,
                                                   const float* __restrict__ s2,
                                                   const float* __restrict__ ah,
                                                   const float* __restrict__ bh,
                                                   int* __restrict__ counts) {
    __shared__ int hist[8];
    if (threadIdx.x < 8) hist[threadIdx.x] = 0;
    __syncthreads();
    int q = blockIdx.x * 256 + threadIdx.x;
    int n = q / HW_;
    int p = q - n * HW_;
    int h = p / W_;
    int w = p - h * W_;
    float dot = 0.f, ss = 0.f;
#pragma unroll
    for (int kk = 0; kk < 9; ++kk) {
        int dh = kk / 3 - 1, dw = kk % 3 - 1;
        int hh = h + dh, ww = w + dw;
        if (hh >= 0 && hh < H_ && ww >= 0 && ww < W_) {
            int idx = n * HW_ + hh * W_ + ww;
            dot += g[(size_t)kk * NPIX + idx];
            ss  += s2[idx];
        }
    }
    float qext = 0.5f * (ah[SPAN_] + ah[SPAN_ + 1] + ah[SPAN_ + 2]);
    float v = dot / sqrtf(ss) + qext;
    int b = bucketf(v, bh[0]);
    atomicAdd(&hist[b], 1);
    __syncthreads();
    if (threadIdx.x < 8) atomicAdd(&counts[threadIdx.x], hist[threadIdx.x]);
}

// ---- Kernel C: argmax bucket + ordered compaction (512-thread scan) ---------
__global__ __launch_bounds__(512) void select_kernel(const int* __restrict__ counts,
                                                     const int* __restrict__ kbuck,
                                                     int* __restrict__ rowsb,
                                                     int* __restrict__ meta,
                                                     float* __restrict__ out,
                                                     int oc_total) {
    __shared__ int sBest;
    __shared__ int sScan[512];
    int t = threadIdx.x;
    if (t == 0) {
        int best = 0, bc = counts[0];
        for (int i = 1; i < 8; ++i) {
            int c = counts[i];
            if (c > bc) { bc = c; best = i; }   // first max wins
        }
        sBest = best;
    }
    __syncthreads();
    int best = sBest;
    int flag = (kbuck[t] == best) ? 1 : 0;
    sScan[t] = flag;
    __syncthreads();
    for (int off = 1; off < 512; off <<= 1) {
        int add = (t >= off) ? sScan[t - off] : 0;
        __syncthreads();
        sScan[t] += add;
        __syncthreads();
    }
    int cnt = sScan[511];
    int pos = sScan[t] - flag;                  // exclusive prefix
    if (flag) rowsb[pos] = t;
    if (cnt == 0) rowsb[t] = t;                 // use-all fallback
    else if (t >= cnt) rowsb[t] = 0;            // safety fill
    if (t == 0) {
        meta[0] = cnt;
        meta[1] = (cnt == 0) ? OUTC : cnt;
    }
    float* rout = out + (size_t)N_ * oc_total * HW_;
    int eff = (cnt == 0) ? OUTC : cnt;
    int nw = eff < oc_total ? eff : oc_total;
    if (cnt == 0) {
        if (t < nw) rout[t] = (float)t;
    } else if (flag && pos < nw) {
        rout[pos] = (float)t;
    }
}

// ---- Kernel P2: gather active rows -> MFMA B-fragment order bf16 -------------
__global__ __launch_bounds__(256) void prep_w(const float* __restrict__ kern,
                                              const int* __restrict__ rowsb,
                                              const int* __restrict__ meta,
                                              const int* __restrict__ mode,
                                              u16* __restrict__ wfrag, int nf4) {
    int e = blockIdx.x * 256 + threadIdx.x;
    int lane = e & 63;
    int t2 = e >> 6;
    int g = t2 % nf4;
    int s = t2 / nf4;                    // 0..71
    int kk = s >> 3;
    int cb = s & 7;
    int q = lane >> 4;
    int mcol = lane & 15;
    int ocEff = meta[1];
    int cnt = meta[0];
    float scale = (mode[0] && cnt > 0) ? 512.0f / (float)cnt : 1.0f;
    int oc_i = g * 16 + mcol;
    bool valid = oc_i < ocEff;
    int row = valid ? rowsb[oc_i] : 0;
    const float* kr = kern + (size_t)row * SPAN_;
    u16 w8[8];
#pragma unroll
    for (int j = 0; j < 8; ++j) {
        int c = cb * 32 + q * 8 + j;
        float v = valid ? kr[c * 9 + kk] * scale : 0.f;
        w8[j] = f2bf(v);
    }
    u16* dst = wfrag + ((size_t)((s * nf4 + g) * 64 + lane)) * 8;
#pragma unroll
    for (int j = 0; j < 8; ++j) dst[j] = w8[j];
}

// ---- Kernel D: MFMA implicit-GEMM conv --------------------------------------
// 4 waves/block, block tile 256 px x 64 oc. A staged via global_load_lds into a
// double-buffered, quarter-XOR-swizzled LDS halo (1 barrier per 32-ch step);
// B register-pipelined TWO kk ahead (3-slot ring), continuous across cb.
__global__ __launch_bounds__(256, 3) void conv_mfma(const u16* __restrict__ xp,
                                                    const u16* __restrict__ wfrag,
                                                    float* __restrict__ out,
                                                    int nf4, int oc_total, int nby) {
    __shared__ char halo[2 * HBYTES + 64];         // 2 bufs + zero slot

    // XCD swizzle: oc-sibling blocks co-located on one XCD; 196 bx = 24*8 + 4.
    int flat = blockIdx.x;
    int bx, by;
    int full = 192 * nby;
    if (flat < full) {
        int gsz = 8 * nby;
        int gi = flat / gsz;
        int tr = flat - gi * gsz;
        by = tr >> 3;
        bx = gi * 8 + (tr & 7);
    } else {
        int tr = flat - full;
        by = tr >> 2;
        bx = 192 + (tr & 3);
    }

    const int t = threadIdx.x;
    const int lane = t & 63;
    const int wv = t >> 6;                         // 0..3
    const int pb = bx * BLKPX;
    const int fb = by * 4;
    const int lane15 = lane & 15;
    const int laneq  = lane >> 4;

    // zero slot (read target for invalid taps)
    if (t < 4) *(u16x8*)&halo[ZOFF + t * 16] = (u16x8){0,0,0,0,0,0,0,0};

    // per-fragment validity masks (bit kk) + swizzled LDS read bases per dw
    u32 valMask[4];
    int aB[4][3];
#pragma unroll
    for (int f = 0; f < 4; ++f) {
        int p = pb + wv * 64 + f * 16 + lane15;
        int img = p / HW_;
        int rp = p - img * HW_;
        int h = rp / W_;
        int w = rp - h * W_;
        u32 m = 0;
#pragma unroll
        for (int kk = 0; kk < 9; ++kk) {
            int dh = kk / 3 - 1, dw = kk % 3 - 1;
            int hh = h + dh, ww = w + dw;
            if (hh >= 0 && hh < H_ && ww >= 0 && ww < W_) m |= (1u << kk);
        }
        valMask[f] = m;
#pragma unroll
        for (int j = 0; j < 3; ++j) {               // dw = j-1
            int sn = 57 + wv * 64 + f * 16 + lane15 + (j - 1);
            aB[f][j] = sn * 64 + ((laneq ^ ((sn >> 1) & 3)) << 4);
        }
    }

    f32x4 acc[4][4];
#pragma unroll
    for (int f = 0; f < 4; ++f)
#pragma unroll
        for (int gg = 0; gg < 4; ++gg) acc[f][gg] = (f32x4){0.f, 0.f, 0.f, 0.f};

    // staging: 6 global_load_lds_dwordx4/thread; LDS dest linear t*16;
    // global source quarter pre-swizzled: q' = (t&3) ^ ((t>>3)&3)
    const char* xpb = (const char*)xp;
    const int q4 = (((t & 3) ^ ((t >> 3) & 3)) << 4);
    int gpx[6];
#pragma unroll
    for (int r = 0; r < 6; ++r) {
        int p = pb - 57 + r * 64 + (t >> 2);
        gpx[r] = p < 0 ? 0 : (p >= NPIX ? NPIX - 1 : p);
    }

    // prologue: stage cb=0 into buf 0
#pragma unroll
    for (int r = 0; r < 6; ++r)
        __builtin_amdgcn_global_load_lds(
            (const __attribute__((address_space(1))) unsigned int*)
                (xpb + (size_t)gpx[r] * 512 + q4),
            (__attribute__((address_space(3))) unsigned int*)&halo[r * 4096 + t * 16],
            16, 0, 0);

    // B: 3-slot register ring, prefetch distance 2
    const size_t cbStride = (size_t)nf4 * 512;
    const size_t kkStride = cbStride * 8;
    const u16* wl = wfrag + (size_t)fb * 512 + (size_t)lane * 8;
    bf16x8 bB[3][4];
#define LOADB(slot, cb_, kk_) do {                                              \
    const u16* _wp = wl + (size_t)(kk_) * kkStride + (size_t)(cb_) * cbStride;  \
    _Pragma("unroll")                                                           \
    for (int _g = 0; _g < 4; ++_g)                                              \
        bB[slot][_g] = *(const bf16x8*)(_wp + (size_t)_g * 512);                \
} while (0)

    LOADB(0, 0, 0);
    LOADB(1, 0, 1);

    for (int cb = 0; cb < 8; ++cb) {
        __syncthreads();                           // buf[cb&1] ready
        const int hoff = (cb & 1) * HBYTES;

        if (cb < 7) {                              // stage next cb into other buf
            const int nb = ((cb + 1) & 1) * HBYTES;
#pragma unroll
            for (int r = 0; r < 6; ++r)
                __builtin_amdgcn_global_load_lds(
                    (const __attribute__((address_space(1))) unsigned int*)
                        (xpb + (size_t)gpx[r] * 512 + (cb + 1) * 64 + q4),
                    (__attribute__((address_space(3))) unsigned int*)
                        &halo[nb + r * 4096 + t * 16],
                    16, 0, 0);
        }

#pragma unroll
        for (int kk = 0; kk < 9; ++kk) {
            // B prefetch, distance 2, continuous across cb
            if (kk < 7)            LOADB((kk + 2) % 3, cb, kk + 2);
            else if (cb < 7)       LOADB((kk + 2) % 3, cb + 1, kk - 7);

            const int dh = kk / 3 - 1;
            const int j  = kk % 3;                 // dw + 1
            const int toffH = hoff + dh * 3584;    // dh * 56 * 64
            bf16x8 aX[4];
#pragma unroll
            for (int f = 0; f < 4; ++f) {
                int addr = ((valMask[f] >> kk) & 1) ? (aB[f][j] + toffH) : ZOFF;
                aX[f] = *(const bf16x8*)&halo[addr];
            }
#pragma unroll
            for (int gg = 0; gg < 4; ++gg)
#pragma unroll
                for (int f = 0; f < 4; ++f)
                    acc[f][gg] = __builtin_amdgcn_mfma_f32_16x16x32_bf16(
                        aX[f], bB[kk % 3][gg], acc[f][gg], 0, 0, 0);
        }
    }
#undef LOADB

    // epilogue: D row (pixel) = (lane>>4)*4 + r, col (oc) = lane&15
#pragma unroll
    for (int f = 0; f < 4; ++f) {
        int p0 = pb + wv * 64 + f * 16 + laneq * 4;
        int img0 = p0 / HW_;
        int hw0 = p0 - img0 * HW_;
#pragma unroll
        for (int gg = 0; gg < 4; ++gg) {
            int oc = (fb + gg) * 16 + lane15;
            if (oc < oc_total) {
                float* op = out + ((size_t)img0 * oc_total + oc) * HW_ + hw0;
                *(f32x4*)op = acc[f][gg];
            }
        }
    }
}

extern "C" void kernel_launch(void* const* d_in, const int* in_sizes, int n_in,
                              void* d_out, int out_size, void* d_ws, size_t ws_size,
                              hipStream_t stream) {
    const float* x    = (const float*)d_in[0];
    const float* kern = (const float*)d_in[1];
    const float* ah   = (const float*)d_in[2];
    const float* bh   = (const float*)d_in[3];
    const int*   mode = (const int*)d_in[4];
    float* out = (float*)d_out;

    // oc is data-dependent but recoverable from out_size: oc*(16*3136+1)
    int oc_total = (out_size % (N_ * HW_ + 1) == 0) ? out_size / (N_ * HW_ + 1)
                                                    : OUTC;
    int nfTot = (oc_total + 15) / 16;
    int nf4   = ((nfTot + 3) / 4) * 4;       // pad fragments to multiple of 4
    int nby   = nf4 / 4;

    // workspace layout (sized for worst case nf4 = 32)
    u16*   xp     = (u16*)d_ws;                                  // NPIX*256
    u16*   wfrag  = xp + (size_t)NPIX * C_;                      // 72*32*64*8
    float* g      = (float*)(wfrag + (size_t)72 * 32 * 64 * 8);  // 9*NPIX
    float* s2     = g + (size_t)9 * NPIX;                        // NPIX
    int*   counts = (int*)(s2 + NPIX);                           // 8
    int*   kbuck  = counts + 8;                                  // 512
    int*   rowsb  = kbuck + OUTC;                                // 512
    int*   meta   = rowsb + OUTC;                                // 2

    hipMemsetAsync(counts, 0, 8 * sizeof(int), stream);

    prep_fused<<<NPIX / 64, 256, 0, stream>>>(x, ah, xp, g, s2);

    kbucket_kernel<<<OUTC, 64, 0, stream>>>(kern, ah, bh, kbuck);
    vote_kernel<<<NPIX / 256, 256, 0, stream>>>(g, s2, ah, bh, counts);
    select_kernel<<<1, 512, 0, stream>>>(counts, kbuck, rowsb, meta, out, oc_total);

    prep_w<<<18 * nf4, 256, 0, stream>>>(kern, rowsb, meta, mode, wfrag, nf4);

    conv_mfma<<<(NPIX / BLKPX) * nby, 256, 0, stream>>>(xp, wfrag, out, nf4,
                                                        oc_total, nby);
}

// Round 9
// 106.611 us; speedup vs baseline: 1.0643x; 1.0643x over previous
//
#include <hip/hip_runtime.h>
#include <math.h>

#define N_    16
#define C_    256
#define H_    56
#define W_    56
#define HW_   3136          // H_*W_
#define NPIX  50176         // N_*HW_
#define OUTC  512
#define SPAN_ 2304          // C_*9
#define BLKPX 256           // conv block pixel tile
#define HBYTES 24576        // one halo buffer: 384 slots * 64 B

typedef unsigned short u16;
typedef unsigned int   u32;
typedef __attribute__((ext_vector_type(8))) short bf16x8;
typedef __attribute__((ext_vector_type(8))) unsigned short u16x8;
typedef __attribute__((ext_vector_type(4))) float f32x4;
typedef __attribute__((ext_vector_type(4))) unsigned short u16x4;

__device__ __forceinline__ u16 f2bf(float v) {
    u32 x = __float_as_uint(v);
    u32 r = (x + 0x7fffu + ((x >> 16) & 1u)) >> 16;   // RNE
    return (u16)r;
}

__device__ __forceinline__ int bucketf(float v, float b) {
    int idx = (int)floorf((v + b) / 2.5f);
    int r = idx % 8;
    return r < 0 ? -r : r;
}

// ---- Kernel P1+B1(+A) fused: NCHW f32 -> NHWC bf16, tap maps g, sumsq s2 ----
// grid = NPIX/64 + 8; the 8 tail blocks compute kbucket (64 oc each).
__global__ __launch_bounds__(256) void prep_fused(const float* __restrict__ x,
                                                  const float* __restrict__ ah,
                                                  const float* __restrict__ bh,
                                                  const float* __restrict__ kern,
                                                  u16* __restrict__ xp,
                                                  float* __restrict__ g,
                                                  float* __restrict__ s2,
                                                  int* __restrict__ kbuck) {
    int kb = blockIdx.x - (NPIX / 64);
    int t = threadIdx.x;
    if (kb >= 0) {
        // ---- kbucket: 64 oc per block, 4 threads per oc ----
        int oc_l = t >> 2, part = t & 3;
        int oc = kb * 64 + oc_l;
        const float* kr = kern + (size_t)oc * SPAN_ + part * 576;
        const float* ap = ah + part * 576;
        float dot = 0.f, ss = 0.f;
        for (int i = 0; i < 144; ++i) {
            float4 kv = *(const float4*)(kr + i * 4);
            float4 av = *(const float4*)(ap + i * 4);
            dot += kv.x * av.x + kv.y * av.y + kv.z * av.z + kv.w * av.w;
            ss  += kv.x * kv.x + kv.y * kv.y + kv.z * kv.z + kv.w * kv.w;
        }
        dot += __shfl_xor(dot, 1); dot += __shfl_xor(dot, 2);
        ss  += __shfl_xor(ss, 1);  ss  += __shfl_xor(ss, 2);
        if (part == 0) {
            float n2 = ss;            // ||k||^2
            float n4 = n2 * n2;
            float n8 = n4 * n4;
            float v = dot + n2 * ah[SPAN_] + n4 * ah[SPAN_ + 1] +
                      n8 * ah[SPAN_ + 2];
            kbuck[oc] = bucketf(v, bh[0]);
        }
        return;
    }

    __shared__ float aL[SPAN_];          // 9216 B
    __shared__ u16 tl[64][68];           // 8704 B
    __shared__ float red[4][64][10];     // 10240 B
    for (int j = t; j < SPAN_; j += 256) aL[j] = ah[j];

    int px0 = blockIdx.x * 64;
    int img = px0 / HW_;
    int hw0 = px0 - img * HW_;
    int px_l = t & 63;
    int cq   = t >> 6;                   // 0..3
    float pg[9];
#pragma unroll
    for (int kk = 0; kk < 9; ++kk) pg[kk] = 0.f;
    float ps = 0.f;
    __syncthreads();

    for (int cb0 = 0; cb0 < 4; ++cb0) {
        int c0 = cb0 * 64;
#pragma unroll
        for (int rep = 0; rep < 16; ++rep) {
            int c_l = rep * 4 + cq;
            float v = x[((size_t)(img * C_ + c0 + c_l)) * HW_ + hw0 + px_l];
            tl[px_l][c_l] = f2bf(v);
            const float* ac = &aL[(c0 + c_l) * 9];
#pragma unroll
            for (int kk = 0; kk < 9; ++kk) pg[kk] += ac[kk] * v;
            ps += v * v;
        }
        __syncthreads();
        int c4  = t & 15;
        int pxs = t >> 4;
#pragma unroll
        for (int rep = 0; rep < 4; ++rep) {
            int pl = rep * 16 + pxs;
            u16x4 v4 = *(const u16x4*)(&tl[pl][c4 * 4]);
            *(u16x4*)(&xp[((size_t)(px0 + pl)) * C_ + c0 + c4 * 4]) = v4;
        }
        __syncthreads();
    }

#pragma unroll
    for (int kk = 0; kk < 9; ++kk) red[cq][px_l][kk] = pg[kk];
    red[cq][px_l][9] = ps;
    __syncthreads();
    for (int it = t; it < 640; it += 256) {
        int pl = it / 10;
        int j  = it - pl * 10;
        float s = red[0][pl][j] + red[1][pl][j] + red[2][pl][j] + red[3][pl][j];
        int q = px0 + pl;
        if (j < 9) g[(size_t)j * NPIX + q] = s;
        else       s2[q] = s;
    }
}

// ---- Kernel B2: per-column vote -> histogram --------------------------------
__global__ __launch_bounds__(256) void vote_kernel(const float* __restrict__ g,
                                                   const float* __restrict__ s2,
                                                   const float* __restrict__ ah,
                                                   const float* __restrict__ bh,
                                                   int* __restrict__ counts) {
    __shared__ int hist[8];
    if (threadIdx.x < 8) hist[threadIdx.x] = 0;
    __syncthreads();
    int q = blockIdx.x * 256 + threadIdx.x;
    int n = q / HW_;
    int p = q - n * HW_;
    int h = p / W_;
    int w = p - h * W_;
    float dot = 0.f, ss = 0.f;
#pragma unroll
    for (int kk = 0; kk < 9; ++kk) {
        int dh = kk / 3 - 1, dw = kk % 3 - 1;
        int hh = h + dh, ww = w + dw;
        if (hh >= 0 && hh < H_ && ww >= 0 && ww < W_) {
            int idx = n * HW_ + hh * W_ + ww;
            dot += g[(size_t)kk * NPIX + idx];
            ss  += s2[idx];
        }
    }
    float qext = 0.5f * (ah[SPAN_] + ah[SPAN_ + 1] + ah[SPAN_ + 2]);
    float v = dot / sqrtf(ss) + qext;
    int b = bucketf(v, bh[0]);
    atomicAdd(&hist[b], 1);
    __syncthreads();
    if (threadIdx.x < 8) atomicAdd(&counts[threadIdx.x], hist[threadIdx.x]);
}

// ---- Kernel P2: self-selecting weight fragmentation -------------------------
// Each block recomputes argmax + 512-wide compaction scan locally (cheap),
// then fragments its share of the active rows. Block 0 also writes the rows
// output section. Removes the single-block select_kernel launch entirely.
__global__ __launch_bounds__(256) void prep_w(const float* __restrict__ kern,
                                              const int* __restrict__ kbuck,
                                              const int* __restrict__ counts,
                                              const int* __restrict__ mode,
                                              float* __restrict__ out,
                                              u16* __restrict__ wfrag,
                                              int nfB, int oc_total) {
    __shared__ int sc[256];
    __shared__ int rowsL[512];
    int t = threadIdx.x;
    int best = 0, bc = counts[0];
#pragma unroll
    for (int i = 1; i < 8; ++i) {
        int c = counts[i];
        if (c > bc) { bc = c; best = i; }   // first max wins
    }
    int f0 = (kbuck[t] == best) ? 1 : 0;
    int f1 = (kbuck[t + 256] == best) ? 1 : 0;
    sc[t] = f0 | (f1 << 16);
    __syncthreads();
    for (int off = 1; off < 256; off <<= 1) {
        int add = (t >= off) ? sc[t - off] : 0;
        __syncthreads();
        sc[t] += add;
        __syncthreads();
    }
    int tot = sc[255];
    int t0  = tot & 0xffff;
    int cnt = t0 + (tot >> 16);
    int pos0 = (sc[t] & 0xffff) - f0;
    int pos1 = t0 + (sc[t] >> 16) - f1;
    rowsL[t] = 0; rowsL[t + 256] = 0;
    __syncthreads();
    if (cnt == 0) { rowsL[t] = t; rowsL[t + 256] = t + 256; }
    else {
        if (f0) rowsL[pos0] = t;
        if (f1) rowsL[pos1] = t + 256;
    }
    __syncthreads();
    int ocEff = (cnt == 0) ? OUTC : cnt;
    float scale = (mode[0] && cnt > 0) ? 512.0f / (float)cnt : 1.0f;

    if (blockIdx.x == 0) {                       // rows output (read as f32)
        float* rout = out + (size_t)N_ * oc_total * HW_;
        int nw = ocEff < oc_total ? ocEff : oc_total;
        if (cnt == 0) {
            if (t < nw) rout[t] = (float)t;
            if (t + 256 < nw) rout[t + 256] = (float)(t + 256);
        } else {
            if (f0 && pos0 < nw) rout[pos0] = (float)t;
            if (f1 && pos1 < nw) rout[pos1] = (float)(t + 256);
        }
    }

    // fragmentation: wfrag elem offset ((s*nfB + g)*64 + lane)*8, K = kk*256+c
    int e = blockIdx.x * 256 + t;
    int lane = e & 63;
    int t2 = e >> 6;
    int g = t2 % nfB;
    int s = t2 / nfB;                    // 0..71
    int kk = s >> 3;
    int cb = s & 7;
    int q = lane >> 4;
    int mcol = lane & 15;
    int oc_i = g * 16 + mcol;
    bool valid = oc_i < ocEff;
    int row = valid ? rowsL[oc_i] : 0;
    const float* kr = kern + (size_t)row * SPAN_;
    u16 w8[8];
#pragma unroll
    for (int j = 0; j < 8; ++j) {
        int c = cb * 32 + q * 8 + j;
        float v = valid ? kr[c * 9 + kk] * scale : 0.f;
        w8[j] = f2bf(v);
    }
    u16* dst = wfrag + ((size_t)((s * nfB + g) * 64 + lane)) * 8;
#pragma unroll
    for (int j = 0; j < 8; ++j) dst[j] = w8[j];
}

// ---- Kernel D: MFMA implicit-GEMM conv --------------------------------------
// 4 waves/block, block tile 256 px x 48 oc (3 frags, zero padding waste).
// A staged via global_load_lds into a double-buffered quarter-XOR-swizzled LDS
// halo (1 barrier per 32-ch step, fully unrolled -> ds_read immediate offsets);
// B register-pipelined one kk ahead, continuous across the cb seam.
__global__ __launch_bounds__(256, 2) void conv_mfma(const u16* __restrict__ xp,
                                                    const u16* __restrict__ wfrag,
                                                    float* __restrict__ out,
                                                    int nfB, int oc_total, int nby) {
    __shared__ char halo[2 * HBYTES];              // 49152 B

    // XCD swizzle: oc-sibling blocks co-located on one XCD; 196 bx = 24*8 + 4.
    int flat = blockIdx.x;
    int bx, by;
    int full = 192 * nby;
    if (flat < full) {
        int gsz = 8 * nby;
        int gi = flat / gsz;
        int tr = flat - gi * gsz;
        by = tr >> 3;
        bx = gi * 8 + (tr & 7);
    } else {
        int tr = flat - full;
        by = tr >> 2;
        bx = 192 + (tr & 3);
    }

    const int t = threadIdx.x;
    const int lane = t & 63;
    const int wv = t >> 6;                         // 0..3
    const int pb = bx * BLKPX;
    const int fb = by * 3;
    const int lane15 = lane & 15;
    const int laneq  = lane >> 4;

    // per-fragment validity masks (bit kk) + swizzled LDS read bases per dw.
    // base holds -3584 bias so the ds_read immediate (dh+1)*3584 stays >= 0.
    u32 valMask[4];
    int aB[4][3];
#pragma unroll
    for (int f = 0; f < 4; ++f) {
        int p = pb + wv * 64 + f * 16 + lane15;
        int img = p / HW_;
        int rp = p - img * HW_;
        int h = rp / W_;
        int w = rp - h * W_;
        u32 m = 0;
#pragma unroll
        for (int kk = 0; kk < 9; ++kk) {
            int dh = kk / 3 - 1, dw = kk % 3 - 1;
            int hh = h + dh, ww = w + dw;
            if (hh >= 0 && hh < H_ && ww >= 0 && ww < W_) m |= (1u << kk);
        }
        valMask[f] = m;
#pragma unroll
        for (int j = 0; j < 3; ++j) {               // dw = j-1
            int sn = 57 + wv * 64 + f * 16 + lane15 + (j - 1);
            aB[f][j] = sn * 64 + ((laneq ^ ((sn >> 1) & 3)) << 4) - 3584;
        }
    }

    f32x4 acc[4][3];
#pragma unroll
    for (int f = 0; f < 4; ++f)
#pragma unroll
        for (int gg = 0; gg < 3; ++gg) acc[f][gg] = (f32x4){0.f, 0.f, 0.f, 0.f};
    const bf16x8 zf = {0, 0, 0, 0, 0, 0, 0, 0};

    // staging: 6 global_load_lds_dwordx4/thread; LDS dest linear t*16;
    // global source quarter pre-swizzled: q' = (t&3) ^ ((t>>3)&3)
    const char* xpb = (const char*)xp;
    const int q4 = (((t & 3) ^ ((t >> 3) & 3)) << 4);
    int gpx[6];
#pragma unroll
    for (int r = 0; r < 6; ++r) {
        int p = pb - 57 + r * 64 + (t >> 2);
        gpx[r] = p < 0 ? 0 : (p >= NPIX ? NPIX - 1 : p);
    }

    // prologue: stage cb=0 into buf 0, load B(cb=0,kk=0)
#pragma unroll
    for (int r = 0; r < 6; ++r)
        __builtin_amdgcn_global_load_lds(
            (const __attribute__((address_space(1))) unsigned int*)
                (xpb + (size_t)gpx[r] * 512 + q4),
            (__attribute__((address_space(3))) unsigned int*)&halo[r * 4096 + t * 16],
            16, 0, 0);

    const size_t cbStride = (size_t)nfB * 512;
    const size_t kkStride = cbStride * 8;
    const u16* wl = wfrag + (size_t)fb * 512 + (size_t)lane * 8;
    bf16x8 bW[3], bWn[3];
#define LOADB(dst, cb_, kk_) do {                                               \
    const u16* _wp = wl + (size_t)(kk_) * kkStride + (size_t)(cb_) * cbStride;  \
    _Pragma("unroll")                                                           \
    for (int _g = 0; _g < 3; ++_g)                                              \
        dst[_g] = *(const bf16x8*)(_wp + (size_t)_g * 512);                     \
} while (0)

    LOADB(bW, 0, 0);

#pragma unroll
    for (int cb = 0; cb < 8; ++cb) {
        __syncthreads();                           // buf[cb&1] ready

        if (cb < 7) {                              // stage next cb, other buf
            const int nb = ((cb + 1) & 1) * HBYTES;
#pragma unroll
            for (int r = 0; r < 6; ++r)
                __builtin_amdgcn_global_load_lds(
                    (const __attribute__((address_space(1))) unsigned int*)
                        (xpb + (size_t)gpx[r] * 512 + (cb + 1) * 64 + q4),
                    (__attribute__((address_space(3))) unsigned int*)
                        &halo[nb + r * 4096 + t * 16],
                    16, 0, 0);
        }

#pragma unroll
        for (int kk = 0; kk < 9; ++kk) {
            // B prefetch distance 1, continuous across the cb seam
            if (kk < 8)       LOADB(bWn, cb, kk + 1);
            else if (cb < 7)  LOADB(bWn, cb + 1, 0);

            const int dh = kk / 3 - 1;
            const int j  = kk % 3;                 // dw + 1
            const int IMM = (cb & 1) * HBYTES + (dh + 1) * 3584;  // compile-time
            bf16x8 aX[4];
#pragma unroll
            for (int f = 0; f < 4; ++f) {
                bf16x8 a = *(const bf16x8*)&halo[aB[f][j] + IMM];
                aX[f] = ((valMask[f] >> kk) & 1) ? a : zf;
            }
#pragma unroll
            for (int gg = 0; gg < 3; ++gg)
#pragma unroll
                for (int f = 0; f < 4; ++f)
                    acc[f][gg] = __builtin_amdgcn_mfma_f32_16x16x32_bf16(
                        aX[f], bW[gg], acc[f][gg], 0, 0, 0);
            if (kk < 8 || cb < 7) {
#pragma unroll
                for (int gg = 0; gg < 3; ++gg) bW[gg] = bWn[gg];
            }
        }
    }
#undef LOADB

    // epilogue: D row (pixel) = (lane>>4)*4 + r, col (oc) = lane&15
#pragma unroll
    for (int f = 0; f < 4; ++f) {
        int p0 = pb + wv * 64 + f * 16 + laneq * 4;
        int img0 = p0 / HW_;
        int hw0 = p0 - img0 * HW_;
#pragma unroll
        for (int gg = 0; gg < 3; ++gg) {
            int oc = (fb + gg) * 16 + lane15;
            if (oc < oc_total) {
                float* op = out + ((size_t)img0 * oc_total + oc) * HW_ + hw0;
                *(f32x4*)op = acc[f][gg];
            }
        }
    }
}

extern "C" void kernel_launch(void* const* d_in, const int* in_sizes, int n_in,
                              void* d_out, int out_size, void* d_ws, size_t ws_size,
                              hipStream_t stream) {
    const float* x    = (const float*)d_in[0];
    const float* kern = (const float*)d_in[1];
    const float* ah   = (const float*)d_in[2];
    const float* bh   = (const float*)d_in[3];
    const int*   mode = (const int*)d_in[4];
    float* out = (float*)d_out;

    // oc is data-dependent but recoverable from out_size: oc*(16*3136+1)
    int oc_total = (out_size % (N_ * HW_ + 1) == 0) ? out_size / (N_ * HW_ + 1)
                                                    : OUTC;
    int nfTot = (oc_total + 15) / 16;
    int nby   = (nfTot + 2) / 3;             // 3 fragments (48 oc) per block
    int nfB   = nby * 3;

    // workspace layout (sized for worst case nfB = 36)
    u16*   xp     = (u16*)d_ws;                                  // NPIX*256
    u16*   wfrag  = xp + (size_t)NPIX * C_;                      // 72*36*64*8
    float* g      = (float*)(wfrag + (size_t)72 * 36 * 64 * 8);  // 9*NPIX
    float* s2     = g + (size_t)9 * NPIX;                        // NPIX
    int*   counts = (int*)(s2 + NPIX);                           // 8
    int*   kbuck  = counts + 8;                                  // 512

    hipMemsetAsync(counts, 0, 8 * sizeof(int), stream);

    prep_fused<<<NPIX / 64 + 8, 256, 0, stream>>>(x, ah, bh, kern, xp, g, s2,
                                                  kbuck);
    vote_kernel<<<NPIX / 256, 256, 0, stream>>>(g, s2, ah, bh, counts);
    prep_w<<<18 * nfB, 256, 0, stream>>>(kern, kbuck, counts, mode, out, wfrag,
                                         nfB, oc_total);
    conv_mfma<<<(NPIX / BLKPX) * nby, 256, 0, stream>>>(xp, wfrag, out, nfB,
                                                        oc_total, nby);
}

// Round 10
// 93.466 us; speedup vs baseline: 1.2140x; 1.1406x over previous
//
#include <hip/hip_runtime.h>
#include <math.h>

#define N_    16
#define C_    256
#define H_    56
#define W_    56
#define HW_   3136          // H_*W_
#define NPIX  50176         // N_*HW_
#define OUTC  512
#define SPAN_ 2304          // C_*9
#define BLKPX 256           // conv block pixel tile
#define HBYTES 24576        // one halo buffer: 384 slots * 64 B
#define PXB   128           // prep2 pixel tile
#define NPB   (NPIX / PXB)  // 392 prep2 pixel blocks

typedef unsigned short u16;
typedef unsigned int   u32;
typedef __attribute__((ext_vector_type(8))) short bf16x8;
typedef __attribute__((ext_vector_type(8))) unsigned short u16x8;
typedef __attribute__((ext_vector_type(4))) float f32x4;
typedef __attribute__((ext_vector_type(4))) unsigned short u16x4;

__device__ __forceinline__ u16 f2bf(float v) {
    u32 x = __float_as_uint(v);
    u32 r = (x + 0x7fffu + ((x >> 16) & 1u)) >> 16;   // RNE
    return (u16)r;
}

__device__ __forceinline__ int bucketf(float v, float b) {
    int idx = (int)floorf((v + b) / 2.5f);
    int r = idx % 8;
    return r < 0 ? -r : r;
}

// ---- Kernel 1: prep2 -- transpose/convert + tap maps + kbucket + zero -------
// grid = NPB + 8. Pixel blocks: 128 threads, one px per thread; all 256
// channels looped in-thread with 16-deep double-buffered load batches.
// 8 tail blocks compute kbucket (64 oc each, 2 threads/oc); tail block 0
// also zeroes counts.
__global__ __launch_bounds__(128) void prep2(const float* __restrict__ x,
                                             const float* __restrict__ ah,
                                             const float* __restrict__ bh,
                                             const float* __restrict__ kern,
                                             u16* __restrict__ xp,
                                             float* __restrict__ g,
                                             float* __restrict__ s2,
                                             int* __restrict__ kbuck,
                                             int* __restrict__ counts) {
    int kb = blockIdx.x - NPB;
    int t = threadIdx.x;
    if (kb >= 0) {
        if (kb == 0 && t < 8) counts[t] = 0;
        int oc_l = t >> 1, part = t & 1;
        int oc = kb * 64 + oc_l;
        const float* kr = kern + (size_t)oc * SPAN_ + part * 1152;
        const float* ap = ah + part * 1152;
        float dot = 0.f, ss = 0.f;
        for (int i = 0; i < 288; ++i) {
            float4 kv = *(const float4*)(kr + i * 4);
            float4 av = *(const float4*)(ap + i * 4);
            dot += kv.x * av.x + kv.y * av.y + kv.z * av.z + kv.w * av.w;
            ss  += kv.x * kv.x + kv.y * kv.y + kv.z * kv.z + kv.w * kv.w;
        }
        dot += __shfl_xor(dot, 1);
        ss  += __shfl_xor(ss, 1);
        if (part == 0) {
            float n2 = ss;            // ||k||^2
            float n4 = n2 * n2;
            float n8 = n4 * n4;
            float v = dot + n2 * ah[SPAN_] + n4 * ah[SPAN_ + 1] +
                      n8 * ah[SPAN_ + 2];
            kbuck[oc] = bucketf(v, bh[0]);
        }
        return;
    }

    __shared__ float aL[SPAN_];          // 9216 B
    __shared__ u16 tl[PXB][68];          // 17408 B
    for (int j = t; j < SPAN_; j += 128) aL[j] = ah[j];

    const int px = blockIdx.x * PXB + t;
    const int img = px / HW_;
    const size_t xbase = (size_t)img * C_ * HW_ + (px - img * HW_);

    float pg[9];
#pragma unroll
    for (int kk = 0; kk < 9; ++kk) pg[kk] = 0.f;
    float ps = 0.f;
    __syncthreads();

    for (int ph = 0; ph < 4; ++ph) {
        float R[16], Rn[16];
#pragma unroll
        for (int i = 0; i < 16; ++i)
            R[i] = x[xbase + (size_t)(ph * 64 + i) * HW_];
#pragma unroll
        for (int sub = 0; sub < 4; ++sub) {
            if (sub < 3) {
#pragma unroll
                for (int i = 0; i < 16; ++i)
                    Rn[i] = x[xbase + (size_t)(ph * 64 + (sub + 1) * 16 + i) * HW_];
            }
#pragma unroll
            for (int i = 0; i < 16; ++i) {
                int c = ph * 64 + sub * 16 + i;
                float v = R[i];
                const float* ac = &aL[c * 9];
#pragma unroll
                for (int kk = 0; kk < 9; ++kk) pg[kk] += ac[kk] * v;
                ps += v * v;
                tl[t][sub * 16 + i] = f2bf(v);
            }
            if (sub < 3) {
#pragma unroll
                for (int i = 0; i < 16; ++i) R[i] = Rn[i];
            }
        }
        __syncthreads();
        // xp write: 16 px-rows x 8 octs per pass, 8 passes
        const int oct = t & 7;
#pragma unroll
        for (int pass = 0; pass < 8; ++pass) {
            int pxl = pass * 16 + (t >> 3);
            u16x8 v8 = *(const u16x8*)&tl[pxl][oct * 8];
            *(u16x8*)&xp[((size_t)(blockIdx.x * PXB + pxl)) * C_ +
                         ph * 64 + oct * 8] = v8;
        }
        __syncthreads();
    }

#pragma unroll
    for (int kk = 0; kk < 9; ++kk) g[(size_t)kk * NPIX + px] = pg[kk];
    s2[px] = ps;
}

// ---- Kernel B2: per-column vote -> histogram --------------------------------
__global__ __launch_bounds__(256) void vote_kernel(const float* __restrict__ g,
                                                   const float* __restrict__ s2,
                                                   const float* __restrict__ ah,
                                                   const float* __restrict__ bh,
                                                   int* __restrict__ counts) {
    __shared__ int hist[8];
    if (threadIdx.x < 8) hist[threadIdx.x] = 0;
    __syncthreads();
    int q = blockIdx.x * 256 + threadIdx.x;
    int n = q / HW_;
    int p = q - n * HW_;
    int h = p / W_;
    int w = p - h * W_;
    float dot = 0.f, ss = 0.f;
#pragma unroll
    for (int kk = 0; kk < 9; ++kk) {
        int dh = kk / 3 - 1, dw = kk % 3 - 1;
        int hh = h + dh, ww = w + dw;
        if (hh >= 0 && hh < H_ && ww >= 0 && ww < W_) {
            int idx = n * HW_ + hh * W_ + ww;
            dot += g[(size_t)kk * NPIX + idx];
            ss  += s2[idx];
        }
    }
    float qext = 0.5f * (ah[SPAN_] + ah[SPAN_ + 1] + ah[SPAN_ + 2]);
    float v = dot / sqrtf(ss) + qext;
    int b = bucketf(v, bh[0]);
    atomicAdd(&hist[b], 1);
    __syncthreads();
    if (threadIdx.x < 8) atomicAdd(&counts[threadIdx.x], hist[threadIdx.x]);
}

// ---- Kernel P2: self-selecting weight fragmentation -------------------------
// Each block recomputes argmax + 512-wide compaction scan locally, then
// fragments its share of the active rows. Block 0 writes the rows output.
__global__ __launch_bounds__(256) void prep_w(const float* __restrict__ kern,
                                              const int* __restrict__ kbuck,
                                              const int* __restrict__ counts,
                                              const int* __restrict__ mode,
                                              float* __restrict__ out,
                                              u16* __restrict__ wfrag,
                                              int nfB, int oc_total) {
    __shared__ int sc[256];
    __shared__ int rowsL[512];
    int t = threadIdx.x;
    int best = 0, bc = counts[0];
#pragma unroll
    for (int i = 1; i < 8; ++i) {
        int c = counts[i];
        if (c > bc) { bc = c; best = i; }   // first max wins
    }
    int f0 = (kbuck[t] == best) ? 1 : 0;
    int f1 = (kbuck[t + 256] == best) ? 1 : 0;
    sc[t] = f0 | (f1 << 16);
    __syncthreads();
    for (int off = 1; off < 256; off <<= 1) {
        int add = (t >= off) ? sc[t - off] : 0;
        __syncthreads();
        sc[t] += add;
        __syncthreads();
    }
    int tot = sc[255];
    int t0  = tot & 0xffff;
    int cnt = t0 + (tot >> 16);
    int pos0 = (sc[t] & 0xffff) - f0;
    int pos1 = t0 + (sc[t] >> 16) - f1;
    rowsL[t] = 0; rowsL[t + 256] = 0;
    __syncthreads();
    if (cnt == 0) { rowsL[t] = t; rowsL[t + 256] = t + 256; }
    else {
        if (f0) rowsL[pos0] = t;
        if (f1) rowsL[pos1] = t + 256;
    }
    __syncthreads();
    int ocEff = (cnt == 0) ? OUTC : cnt;
    float scale = (mode[0] && cnt > 0) ? 512.0f / (float)cnt : 1.0f;

    if (blockIdx.x == 0) {                       // rows output (read as f32)
        float* rout = out + (size_t)N_ * oc_total * HW_;
        int nw = ocEff < oc_total ? ocEff : oc_total;
        if (cnt == 0) {
            if (t < nw) rout[t] = (float)t;
            if (t + 256 < nw) rout[t + 256] = (float)(t + 256);
        } else {
            if (f0 && pos0 < nw) rout[pos0] = (float)t;
            if (f1 && pos1 < nw) rout[pos1] = (float)(t + 256);
        }
    }

    // fragmentation: wfrag elem offset ((s*nfB + g)*64 + lane)*8, K = kk*256+c
    int e = blockIdx.x * 256 + t;
    int lane = e & 63;
    int t2 = e >> 6;
    int g = t2 % nfB;
    int s = t2 / nfB;                    // 0..71
    int kk = s >> 3;
    int cb = s & 7;
    int q = lane >> 4;
    int mcol = lane & 15;
    int oc_i = g * 16 + mcol;
    bool valid = oc_i < ocEff;
    int row = valid ? rowsL[oc_i] : 0;
    const float* kr = kern + (size_t)row * SPAN_;
    u16 w8[8];
#pragma unroll
    for (int j = 0; j < 8; ++j) {
        int c = cb * 32 + q * 8 + j;
        float v = valid ? kr[c * 9 + kk] * scale : 0.f;
        w8[j] = f2bf(v);
    }
    u16* dst = wfrag + ((size_t)((s * nfB + g) * 64 + lane)) * 8;
#pragma unroll
    for (int j = 0; j < 8; ++j) dst[j] = w8[j];
}

// ---- Kernel D: MFMA implicit-GEMM conv --------------------------------------
// 4 waves/block, block tile 256 px x 48 oc (3 frags, zero padding waste).
// A staged via global_load_lds into a double-buffered quarter-XOR-swizzled LDS
// halo (1 barrier per 32-ch step, fully unrolled -> ds_read immediate offsets);
// B register-pipelined one kk ahead, continuous across the cb seam.
__global__ __launch_bounds__(256, 2) void conv_mfma(const u16* __restrict__ xp,
                                                    const u16* __restrict__ wfrag,
                                                    float* __restrict__ out,
                                                    int nfB, int oc_total, int nby) {
    __shared__ char halo[2 * HBYTES];              // 49152 B

    // XCD swizzle: oc-sibling blocks co-located on one XCD; 196 bx = 24*8 + 4.
    int flat = blockIdx.x;
    int bx, by;
    int full = 192 * nby;
    if (flat < full) {
        int gsz = 8 * nby;
        int gi = flat / gsz;
        int tr = flat - gi * gsz;
        by = tr >> 3;
        bx = gi * 8 + (tr & 7);
    } else {
        int tr = flat - full;
        by = tr >> 2;
        bx = 192 + (tr & 3);
    }

    const int t = threadIdx.x;
    const int lane = t & 63;
    const int wv = t >> 6;                         // 0..3
    const int pb = bx * BLKPX;
    const int fb = by * 3;
    const int lane15 = lane & 15;
    const int laneq  = lane >> 4;

    // per-fragment validity masks (bit kk) + swizzled LDS read bases per dw.
    // base holds -3584 bias so the ds_read immediate (dh+1)*3584 stays >= 0.
    u32 valMask[4];
    int aB[4][3];
#pragma unroll
    for (int f = 0; f < 4; ++f) {
        int p = pb + wv * 64 + f * 16 + lane15;
        int img = p / HW_;
        int rp = p - img * HW_;
        int h = rp / W_;
        int w = rp - h * W_;
        u32 m = 0;
#pragma unroll
        for (int kk = 0; kk < 9; ++kk) {
            int dh = kk / 3 - 1, dw = kk % 3 - 1;
            int hh = h + dh, ww = w + dw;
            if (hh >= 0 && hh < H_ && ww >= 0 && ww < W_) m |= (1u << kk);
        }
        valMask[f] = m;
#pragma unroll
        for (int j = 0; j < 3; ++j) {               // dw = j-1
            int sn = 57 + wv * 64 + f * 16 + lane15 + (j - 1);
            aB[f][j] = sn * 64 + ((laneq ^ ((sn >> 1) & 3)) << 4) - 3584;
        }
    }

    f32x4 acc[4][3];
#pragma unroll
    for (int f = 0; f < 4; ++f)
#pragma unroll
        for (int gg = 0; gg < 3; ++gg) acc[f][gg] = (f32x4){0.f, 0.f, 0.f, 0.f};
    const bf16x8 zf = {0, 0, 0, 0, 0, 0, 0, 0};

    // staging: 6 global_load_lds_dwordx4/thread; LDS dest linear t*16;
    // global source quarter pre-swizzled: q' = (t&3) ^ ((t>>3)&3)
    const char* xpb = (const char*)xp;
    const int q4 = (((t & 3) ^ ((t >> 3) & 3)) << 4);
    int gpx[6];
#pragma unroll
    for (int r = 0; r < 6; ++r) {
        int p = pb - 57 + r * 64 + (t >> 2);
        gpx[r] = p < 0 ? 0 : (p >= NPIX ? NPIX - 1 : p);
    }

    // prologue: stage cb=0 into buf 0, load B(cb=0,kk=0)
#pragma unroll
    for (int r = 0; r < 6; ++r)
        __builtin_amdgcn_global_load_lds(
            (const __attribute__((address_space(1))) unsigned int*)
                (xpb + (size_t)gpx[r] * 512 + q4),
            (__attribute__((address_space(3))) unsigned int*)&halo[r * 4096 + t * 16],
            16, 0, 0);

    const size_t cbStride = (size_t)nfB * 512;
    const size_t kkStride = cbStride * 8;
    const u16* wl = wfrag + (size_t)fb * 512 + (size_t)lane * 8;
    bf16x8 bW[3], bWn[3];
#define LOADB(dst, cb_, kk_) do {                                               \
    const u16* _wp = wl + (size_t)(kk_) * kkStride + (size_t)(cb_) * cbStride;  \
    _Pragma("unroll")                                                           \
    for (int _g = 0; _g < 3; ++_g)                                              \
        dst[_g] = *(const bf16x8*)(_wp + (size_t)_g * 512);                     \
} while (0)

    LOADB(bW, 0, 0);

#pragma unroll
    for (int cb = 0; cb < 8; ++cb) {
        __syncthreads();                           // buf[cb&1] ready

        if (cb < 7) {                              // stage next cb, other buf
            const int nb = ((cb + 1) & 1) * HBYTES;
#pragma unroll
            for (int r = 0; r < 6; ++r)
                __builtin_amdgcn_global_load_lds(
                    (const __attribute__((address_space(1))) unsigned int*)
                        (xpb + (size_t)gpx[r] * 512 + (cb + 1) * 64 + q4),
                    (__attribute__((address_space(3))) unsigned int*)
                        &halo[nb + r * 4096 + t * 16],
                    16, 0, 0);
        }

#pragma unroll
        for (int kk = 0; kk < 9; ++kk) {
            // B prefetch distance 1, continuous across the cb seam
            if (kk < 8)       LOADB(bWn, cb, kk + 1);
            else if (cb < 7)  LOADB(bWn, cb + 1, 0);

            const int dh = kk / 3 - 1;
            const int j  = kk % 3;                 // dw + 1
            const int IMM = (cb & 1) * HBYTES + (dh + 1) * 3584;  // compile-time
            bf16x8 aX[4];
#pragma unroll
            for (int f = 0; f < 4; ++f) {
                bf16x8 a = *(const bf16x8*)&halo[aB[f][j] + IMM];
                aX[f] = ((valMask[f] >> kk) & 1) ? a : zf;
            }
#pragma unroll
            for (int gg = 0; gg < 3; ++gg)
#pragma unroll
                for (int f = 0; f < 4; ++f)
                    acc[f][gg] = __builtin_amdgcn_mfma_f32_16x16x32_bf16(
                        aX[f], bW[gg], acc[f][gg], 0, 0, 0);
            if (kk < 8 || cb < 7) {
#pragma unroll
                for (int gg = 0; gg < 3; ++gg) bW[gg] = bWn[gg];
            }
        }
    }
#undef LOADB

    // epilogue: D row (pixel) = (lane>>4)*4 + r, col (oc) = lane&15
#pragma unroll
    for (int f = 0; f < 4; ++f) {
        int p0 = pb + wv * 64 + f * 16 + laneq * 4;
        int img0 = p0 / HW_;
        int hw0 = p0 - img0 * HW_;
#pragma unroll
        for (int gg = 0; gg < 3; ++gg) {
            int oc = (fb + gg) * 16 + lane15;
            if (oc < oc_total) {
                float* op = out + ((size_t)img0 * oc_total + oc) * HW_ + hw0;
                *(f32x4*)op = acc[f][gg];
            }
        }
    }
}

extern "C" void kernel_launch(void* const* d_in, const int* in_sizes, int n_in,
                              void* d_out, int out_size, void* d_ws, size_t ws_size,
                              hipStream_t stream) {
    const float* x    = (const float*)d_in[0];
    const float* kern = (const float*)d_in[1];
    const float* ah   = (const float*)d_in[2];
    const float* bh   = (const float*)d_in[3];
    const int*   mode = (const int*)d_in[4];
    float* out = (float*)d_out;

    // oc is data-dependent but recoverable from out_size: oc*(16*3136+1)
    int oc_total = (out_size % (N_ * HW_ + 1) == 0) ? out_size / (N_ * HW_ + 1)
                                                    : OUTC;
    int nfTot = (oc_total + 15) / 16;
    int nby   = (nfTot + 2) / 3;             // 3 fragments (48 oc) per block
    int nfB   = nby * 3;

    // workspace layout (sized for worst case nfB = 36)
    u16*   xp     = (u16*)d_ws;                                  // NPIX*256
    u16*   wfrag  = xp + (size_t)NPIX * C_;                      // 72*36*64*8
    float* g      = (float*)(wfrag + (size_t)72 * 36 * 64 * 8);  // 9*NPIX
    float* s2     = g + (size_t)9 * NPIX;                        // NPIX
    int*   counts = (int*)(s2 + NPIX);                           // 8
    int*   kbuck  = counts + 8;                                  // 512

    prep2<<<NPB + 8, 128, 0, stream>>>(x, ah, bh, kern, xp, g, s2, kbuck,
                                       counts);
    vote_kernel<<<NPIX / 256, 256, 0, stream>>>(g, s2, ah, bh, counts);
    prep_w<<<18 * nfB, 256, 0, stream>>>(kern, kbuck, counts, mode, out, wfrag,
                                         nfB, oc_total);
    conv_mfma<<<(NPIX / BLKPX) * nby, 256, 0, stream>>>(xp, wfrag, out, nfB,
                                                        oc_total, nby);
}